// Round 1
// baseline (1815.606 us; speedup 1.0000x reference)
//
#include <hip/hip_runtime.h>
#include <math.h>

#define B_   16
#define D_   256
#define T_   4096
#define NQn  8
#define K_   1024
#define DC_  128
#define M_   65536   // B_*T_
#define NB_  8       // K_/128 code blocks

// ---------------------------------------------------------------- utilities
__global__ void zero_acc_k(float* acc) { acc[0] = 0.f; }

__global__ void final_k(const float* __restrict__ acc, float* __restrict__ out) {
    out[0] = acc[0] * (1.f / 262144.f);   // / (4 * B * T)
}

// ---------------------------------------------------------------- xp = X * Win^T + b_in
// X in (B, D, T) layout; block handles 64 t-rows x all 128 c-cols, K = D = 256.
__global__ __launch_bounds__(256) void xp_gemm_k(
    const float* __restrict__ X0,   // (B, D, T)
    const float* __restrict__ Win,  // (DC, D) this quantizer
    const float* __restrict__ bin,  // (DC)
    float* __restrict__ xp)         // (M, DC)
{
    __shared__ float lds_a[64][64];   // [k][m]
    __shared__ float lds_w[64][132];  // [k][c], padded stride
    const int b  = blockIdx.x >> 6;
    const int t0 = (blockIdx.x & 63) << 6;
    const float* Xb = X0 + (size_t)b * D_ * T_;
    const int tid = threadIdx.x;
    const int tn = tid & 31;    // 32 thread-cols x 4 c
    const int tm = tid >> 5;    // 8 thread-rows x 8 m
    float acc[8][4];
    #pragma unroll
    for (int r = 0; r < 8; ++r)
        #pragma unroll
        for (int j = 0; j < 4; ++j) acc[r][j] = 0.f;

    for (int k0 = 0; k0 < D_; k0 += 64) {
        #pragma unroll
        for (int it = 0; it < 16; ++it) {
            int idx = it * 256 + tid;
            int kk = idx >> 6, mm = idx & 63;
            lds_a[kk][mm] = Xb[(size_t)(k0 + kk) * T_ + t0 + mm];
        }
        #pragma unroll
        for (int it = 0; it < 32; ++it) {
            int idx = it * 256 + tid;
            int cc = idx >> 6, kk = idx & 63;
            lds_w[kk][cc] = Win[(size_t)cc * D_ + k0 + kk];
        }
        __syncthreads();
        #pragma unroll 8
        for (int kk = 0; kk < 64; ++kk) {
            float4 a0 = *(const float4*)&lds_a[kk][tm * 8];
            float4 a1 = *(const float4*)&lds_a[kk][tm * 8 + 4];
            float4 w  = *(const float4*)&lds_w[kk][tn * 4];
            float av[8] = {a0.x, a0.y, a0.z, a0.w, a1.x, a1.y, a1.z, a1.w};
            float wv[4] = {w.x, w.y, w.z, w.w};
            #pragma unroll
            for (int r = 0; r < 8; ++r)
                #pragma unroll
                for (int j = 0; j < 4; ++j)
                    acc[r][j] = fmaf(av[r], wv[j], acc[r][j]);
        }
        __syncthreads();
    }
    float bi[4];
    #pragma unroll
    for (int j = 0; j < 4; ++j) bi[j] = bin[tn * 4 + j];
    const size_t row0 = (size_t)b * T_ + t0;
    #pragma unroll
    for (int r = 0; r < 8; ++r) {
        size_t row = row0 + (size_t)(tm * 8 + r);
        float4 o = make_float4(acc[r][0] + bi[0], acc[r][1] + bi[1],
                               acc[r][2] + bi[2], acc[r][3] + bi[3]);
        *(float4*)&xp[row * DC_ + tn * 4] = o;
    }
}

// ---------------------------------------------------------------- e2[k] = |embed[k]|^2
__global__ void e2_k(const float* __restrict__ emb, float* __restrict__ e2) {
    int k = blockIdx.x * 256 + threadIdx.x;
    const float4* row = (const float4*)(emb + (size_t)k * DC_);
    float s = 0.f;
    #pragma unroll
    for (int i = 0; i < 32; ++i) {
        float4 v = row[i];
        s += v.x * v.x + v.y * v.y + v.z * v.z + v.w * v.w;
    }
    e2[k] = s;
}

// ---------------------------------------------------------------- distance GEMM + fused online (max, argmax, sumexp)
// Block: 64 rows x 128 codes, full DC dot. Partials per (row, code-block) to ws.
__global__ __launch_bounds__(256) void dist_k(
    const float* __restrict__ xp,   // (M, DC)
    const float* __restrict__ emb,  // (K, DC)
    const float* __restrict__ e2,   // (K)
    const int*   __restrict__ tlc,  // (B, NQ, T)
    int iq,
    float* __restrict__ pm, float* __restrict__ pl, int* __restrict__ pidx,
    float* __restrict__ picked)
{
    __shared__ float lds_x[64][68];    // [k][m]
    __shared__ float lds_e[64][132];   // [k][c]
    const int row0 = blockIdx.x * 64;
    const int c0   = blockIdx.y * 128;
    const int tid = threadIdx.x;
    const int tn = tid & 31;
    const int tm = tid >> 5;
    float acc[8][4];
    #pragma unroll
    for (int r = 0; r < 8; ++r)
        #pragma unroll
        for (int j = 0; j < 4; ++j) acc[r][j] = 0.f;

    for (int k0 = 0; k0 < DC_; k0 += 64) {
        #pragma unroll
        for (int it = 0; it < 16; ++it) {
            int idx = it * 256 + tid;
            int mm = idx >> 6, kk = idx & 63;
            lds_x[kk][mm] = xp[(size_t)(row0 + mm) * DC_ + k0 + kk];
        }
        #pragma unroll
        for (int it = 0; it < 32; ++it) {
            int idx = it * 256 + tid;
            int cc = idx >> 6, kk = idx & 63;
            lds_e[kk][cc] = emb[(size_t)(c0 + cc) * DC_ + k0 + kk];
        }
        __syncthreads();
        #pragma unroll 8
        for (int kk = 0; kk < 64; ++kk) {
            float4 a0 = *(const float4*)&lds_x[kk][tm * 8];
            float4 a1 = *(const float4*)&lds_x[kk][tm * 8 + 4];
            float4 w  = *(const float4*)&lds_e[kk][tn * 4];
            float av[8] = {a0.x, a0.y, a0.z, a0.w, a1.x, a1.y, a1.z, a1.w};
            float wv[4] = {w.x, w.y, w.z, w.w};
            #pragma unroll
            for (int r = 0; r < 8; ++r)
                #pragma unroll
                for (int j = 0; j < 4; ++j)
                    acc[r][j] = fmaf(av[r], wv[j], acc[r][j]);
        }
        __syncthreads();
    }

    float e2v[4];
    #pragma unroll
    for (int j = 0; j < 4; ++j) e2v[j] = e2[c0 + tn * 4 + j];

    #pragma unroll
    for (int r = 0; r < 8; ++r) {
        int row = row0 + tm * 8 + r;
        float lg[4];
        #pragma unroll
        for (int j = 0; j < 4; ++j)
            lg[j] = fmaf(2.f, acc[r][j], -e2v[j]) * (1.f / 128.f);
        // local max/argmax (ascending j keeps first-occurrence tie rule)
        float m = lg[0]; int bi = c0 + tn * 4;
        #pragma unroll
        for (int j = 1; j < 4; ++j)
            if (lg[j] > m) { m = lg[j]; bi = c0 + tn * 4 + j; }
        float l = 0.f;
        #pragma unroll
        for (int j = 0; j < 4; ++j) l += __expf(lg[j] - m);
        // butterfly over the 32 lanes sharing this row group (half-wave)
        #pragma unroll
        for (int off = 1; off < 32; off <<= 1) {
            float om = __shfl_xor(m, off);
            float ol = __shfl_xor(l, off);
            int   ob = __shfl_xor(bi, off);
            float nm = fmaxf(m, om);
            l = l * __expf(m - nm) + ol * __expf(om - nm);
            if (om > m || (om == m && ob < bi)) bi = ob;
            m = nm;
        }
        if (tn == 0) {
            pm[(size_t)row * NB_ + blockIdx.y]   = m;
            pl[(size_t)row * NB_ + blockIdx.y]   = l;
            pidx[(size_t)row * NB_ + blockIdx.y] = bi;
        }
        int bb = row >> 12, t = row & (T_ - 1);
        int tg = tlc[(size_t)bb * NQn * T_ + (size_t)iq * T_ + t];
        int loc = tg - c0;
        if (loc >= 0 && loc < 128 && (loc >> 2) == tn) {
            int j = loc & 3;
            float pv = (j == 0) ? lg[0] : (j == 1) ? lg[1] : (j == 2) ? lg[2] : lg[3];
            picked[row] = pv;
        }
    }
}

// ---------------------------------------------------------------- combine 8 partials per row -> loss + ind
__global__ __launch_bounds__(256) void reduce_k(
    const float* __restrict__ pm, const float* __restrict__ pl,
    const int* __restrict__ pidx, const float* __restrict__ picked,
    int* __restrict__ ind, float* __restrict__ acc, int needInd)
{
    int row = blockIdx.x * 256 + threadIdx.x;
    const float4* pm4 = (const float4*)(pm + (size_t)row * 8);
    const float4* pl4 = (const float4*)(pl + (size_t)row * 8);
    const int4*   pi4 = (const int4*)(pidx + (size_t)row * 8);
    float4 ma = pm4[0], mb = pm4[1];
    float4 la = pl4[0], lb = pl4[1];
    int4   ia = pi4[0], ib = pi4[1];
    float mv[8] = {ma.x, ma.y, ma.z, ma.w, mb.x, mb.y, mb.z, mb.w};
    float lv[8] = {la.x, la.y, la.z, la.w, lb.x, lb.y, lb.z, lb.w};
    int   iv[8] = {ia.x, ia.y, ia.z, ia.w, ib.x, ib.y, ib.z, ib.w};
    float m = mv[0], l = lv[0]; int bi = iv[0]; float bm = mv[0];
    #pragma unroll
    for (int nb = 1; nb < 8; ++nb) {
        float nm = fmaxf(m, mv[nb]);
        l = l * __expf(m - nm) + lv[nb] * __expf(mv[nb] - nm);
        m = nm;
        if (mv[nb] > bm) { bm = mv[nb]; bi = iv[nb]; }  // strict > keeps lowest block
    }
    float contrib = (m + __logf(l)) - picked[row];
    if (needInd) ind[row] = bi;
    __shared__ float red[256];
    red[threadIdx.x] = contrib;
    __syncthreads();
    #pragma unroll
    for (int s = 128; s > 0; s >>= 1) {
        if (threadIdx.x < s) red[threadIdx.x] += red[threadIdx.x + s];
        __syncthreads();
    }
    if (threadIdx.x == 0) atomicAdd(acc, red[0]);
}

// ---------------------------------------------------------------- table[k][d] = embed[k]·Wout[d] + b_out[d]
__global__ __launch_bounds__(256) void table_k(
    const float* __restrict__ emb, const float* __restrict__ Wout,
    const float* __restrict__ bout, float* __restrict__ table)
{
    __shared__ float se[4][DC_];
    int k0 = blockIdx.x * 4;
    int tid = threadIdx.x;
    #pragma unroll
    for (int it = 0; it < 2; ++it) {
        int idx = it * 256 + tid;
        se[idx >> 7][idx & 127] = emb[(size_t)k0 * DC_ + idx];
    }
    __syncthreads();
    int d = tid;
    const float4* wrow = (const float4*)(Wout + (size_t)d * DC_);
    float a0 = 0.f, a1 = 0.f, a2 = 0.f, a3 = 0.f;
    #pragma unroll
    for (int c4 = 0; c4 < 32; ++c4) {
        float4 w  = wrow[c4];
        float4 q0 = *(const float4*)&se[0][c4 * 4];
        float4 q1 = *(const float4*)&se[1][c4 * 4];
        float4 q2 = *(const float4*)&se[2][c4 * 4];
        float4 q3 = *(const float4*)&se[3][c4 * 4];
        a0 += w.x * q0.x + w.y * q0.y + w.z * q0.z + w.w * q0.w;
        a1 += w.x * q1.x + w.y * q1.y + w.z * q1.z + w.w * q1.w;
        a2 += w.x * q2.x + w.y * q2.y + w.z * q2.z + w.w * q2.w;
        a3 += w.x * q3.x + w.y * q3.y + w.z * q3.z + w.w * q3.w;
    }
    float bo = bout[d];
    table[(size_t)(k0 + 0) * D_ + d] = a0 + bo;
    table[(size_t)(k0 + 1) * D_ + d] = a1 + bo;
    table[(size_t)(k0 + 2) * D_ + d] = a2 + bo;
    table[(size_t)(k0 + 3) * D_ + d] = a3 + bo;
}

// ---------------------------------------------------------------- residual -= table[ind]
__global__ __launch_bounds__(256) void update_k(
    const float* __restrict__ src, const float* __restrict__ table,
    const int* __restrict__ ind, float* __restrict__ dst)
{
    __shared__ int sk[64];
    const int b  = blockIdx.x >> 6;
    const int t0 = (blockIdx.x & 63) << 6;
    const int tid = threadIdx.x;
    if (tid < 64) sk[tid] = ind[(size_t)b * T_ + t0 + tid];
    __syncthreads();
    const int t4 = (tid & 15) * 4;
    const int dg = tid >> 4;
    const int k0 = sk[t4], k1 = sk[t4 + 1], k2 = sk[t4 + 2], k3 = sk[t4 + 3];
    #pragma unroll
    for (int dl = 0; dl < 16; ++dl) {
        int d = dl * 16 + dg;
        size_t base = ((size_t)b * D_ + d) * T_ + t0 + t4;
        float4 v = *(const float4*)&src[base];
        float4 o;
        o.x = v.x - table[(size_t)k0 * D_ + d];
        o.y = v.y - table[(size_t)k1 * D_ + d];
        o.z = v.z - table[(size_t)k2 * D_ + d];
        o.w = v.w - table[(size_t)k3 * D_ + d];
        *(float4*)&dst[base] = o;
    }
}

// ---------------------------------------------------------------- launch
extern "C" void kernel_launch(void* const* d_in, const int* in_sizes, int n_in,
                              void* d_out, int out_size, void* d_ws, size_t ws_size,
                              hipStream_t stream)
{
    (void)in_sizes; (void)n_in; (void)out_size; (void)ws_size;
    const float* dstart = (const float*)d_in[0];
    const int*   tlc    = (const int*)d_in[1];
    const float* Win    = (const float*)d_in[2];
    const float* bin    = (const float*)d_in[3];
    const float* Wout   = (const float*)d_in[4];
    const float* bout   = (const float*)d_in[5];
    const float* emb    = (const float*)d_in[6];

    char* ws = (char*)d_ws;
    size_t off = 0;
    float* xres  = (float*)(ws + off); off += (size_t)B_ * D_ * T_ * 4;   // 67.1 MB
    float* xp    = (float*)(ws + off); off += (size_t)M_ * DC_ * 4;       // 33.6 MB
    float* pm    = (float*)(ws + off); off += (size_t)M_ * NB_ * 4;
    float* pl    = (float*)(ws + off); off += (size_t)M_ * NB_ * 4;
    int*   pidx  = (int*)(ws + off);   off += (size_t)M_ * NB_ * 4;
    float* picked= (float*)(ws + off); off += (size_t)M_ * 4;
    int*   ind   = (int*)(ws + off);   off += (size_t)M_ * 4;
    float* table = (float*)(ws + off); off += (size_t)K_ * D_ * 4;
    float* e2    = (float*)(ws + off); off += (size_t)K_ * 4;
    float* accp  = (float*)(ws + off); off += 256;

    zero_acc_k<<<1, 1, 0, stream>>>(accp);

    for (int i = 0; i < 4; ++i) {
        const float* srcX = (i == 0) ? dstart : xres;
        xp_gemm_k<<<1024, 256, 0, stream>>>(srcX, Win + (size_t)i * DC_ * D_,
                                            bin + (size_t)i * DC_, xp);
        e2_k<<<4, 256, 0, stream>>>(emb + (size_t)i * K_ * DC_, e2);
        dim3 dgrid(1024, 8);
        dist_k<<<dgrid, 256, 0, stream>>>(xp, emb + (size_t)i * K_ * DC_, e2,
                                          tlc, i, pm, pl, pidx, picked);
        reduce_k<<<256, 256, 0, stream>>>(pm, pl, pidx, picked, ind, accp,
                                          (i < 3) ? 1 : 0);
        if (i < 3) {
            table_k<<<256, 256, 0, stream>>>(emb + (size_t)i * K_ * DC_,
                                             Wout + (size_t)i * D_ * DC_,
                                             bout + (size_t)i * D_, table);
            update_k<<<1024, 256, 0, stream>>>((i == 0) ? dstart : xres,
                                               table, ind, xres);
        }
    }
    final_k<<<1, 1, 0, stream>>>(accp, (float*)d_out);
}

// Round 2
// 575.023 us; speedup vs baseline: 3.1575x; 3.1575x over previous
//
#include <hip/hip_runtime.h>
#include <math.h>

#define B_   16
#define D_   256
#define T_   4096
#define NQn  8
#define K_   1024
#define DC_  128
#define M_   65536   // B_*T_

typedef short bf16x8 __attribute__((ext_vector_type(8)));
typedef float f32x4  __attribute__((ext_vector_type(4)));

static __device__ __forceinline__ unsigned short f2bf(float f) {
    unsigned u = __float_as_uint(f);
    unsigned r = (u + 0x7fffu + ((u >> 16) & 1u)) >> 16;
    return (unsigned short)r;
}

// ---------------------------------------------------------------- utilities
__global__ void zero_acc_k(float* acc) { acc[0] = 0.f; }

__global__ void final_k(const float* __restrict__ acc, float* __restrict__ out) {
    out[0] = acc[0] * (1.f / 262144.f);   // / (4 * B * T)
}

// ---------------------------------------------------------------- embed -> bf16, e2/128
__global__ __launch_bounds__(256) void conv_emb_k(
    const float* __restrict__ emb, unsigned short* __restrict__ embb,
    float* __restrict__ e2h)
{
    int code = blockIdx.x * 16 + (threadIdx.x >> 4);   // global code over 4 quantizers
    int part = threadIdx.x & 15;
    const float* src = emb + (size_t)code * DC_ + part * 8;
    float4 a  = *(const float4*)src;
    float4 b2 = *(const float4*)(src + 4);
    float s = a.x*a.x + a.y*a.y + a.z*a.z + a.w*a.w
            + b2.x*b2.x + b2.y*b2.y + b2.z*b2.z + b2.w*b2.w;
    int4 ov;
    unsigned short* op = (unsigned short*)&ov;
    op[0]=f2bf(a.x);  op[1]=f2bf(a.y);  op[2]=f2bf(a.z);  op[3]=f2bf(a.w);
    op[4]=f2bf(b2.x); op[5]=f2bf(b2.y); op[6]=f2bf(b2.z); op[7]=f2bf(b2.w);
    *(int4*)&embb[(size_t)code * DC_ + part * 8] = ov;
    s += __shfl_xor(s, 1); s += __shfl_xor(s, 2);
    s += __shfl_xor(s, 4); s += __shfl_xor(s, 8);
    if (part == 0) e2h[code] = s * 0.0078125f;   // /128
}

// ---------------------------------------------------------------- xp = X * Win^T + b_in  (bf16 out)
__global__ __launch_bounds__(256) void xp_gemm_k(
    const float* __restrict__ X0,   // (B, D, T)
    const float* __restrict__ Win,  // (DC, D) this quantizer
    const float* __restrict__ bin,  // (DC)
    unsigned short* __restrict__ xpb)  // (M, DC) bf16
{
    __shared__ float lds_a[64][64];
    __shared__ float lds_w[64][132];
    const int b  = blockIdx.x >> 6;
    const int t0 = (blockIdx.x & 63) << 6;
    const float* Xb = X0 + (size_t)b * D_ * T_;
    const int tid = threadIdx.x;
    const int tn = tid & 31;
    const int tm = tid >> 5;
    float acc[8][4];
    #pragma unroll
    for (int r = 0; r < 8; ++r)
        #pragma unroll
        for (int j = 0; j < 4; ++j) acc[r][j] = 0.f;

    for (int k0 = 0; k0 < D_; k0 += 64) {
        #pragma unroll
        for (int it = 0; it < 16; ++it) {
            int idx = it * 256 + tid;
            int kk = idx >> 6, mm = idx & 63;
            lds_a[kk][mm] = Xb[(size_t)(k0 + kk) * T_ + t0 + mm];
        }
        #pragma unroll
        for (int it = 0; it < 32; ++it) {
            int idx = it * 256 + tid;
            int cc = idx >> 6, kk = idx & 63;
            lds_w[kk][cc] = Win[(size_t)cc * D_ + k0 + kk];
        }
        __syncthreads();
        #pragma unroll 8
        for (int kk = 0; kk < 64; ++kk) {
            float4 a0 = *(const float4*)&lds_a[kk][tm * 8];
            float4 a1 = *(const float4*)&lds_a[kk][tm * 8 + 4];
            float4 w  = *(const float4*)&lds_w[kk][tn * 4];
            float av[8] = {a0.x, a0.y, a0.z, a0.w, a1.x, a1.y, a1.z, a1.w};
            float wv[4] = {w.x, w.y, w.z, w.w};
            #pragma unroll
            for (int r = 0; r < 8; ++r)
                #pragma unroll
                for (int j = 0; j < 4; ++j)
                    acc[r][j] = fmaf(av[r], wv[j], acc[r][j]);
        }
        __syncthreads();
    }
    float bi[4];
    #pragma unroll
    for (int j = 0; j < 4; ++j) bi[j] = bin[tn * 4 + j];
    const size_t row0 = (size_t)b * T_ + t0;
    #pragma unroll
    for (int r = 0; r < 8; ++r) {
        size_t row = row0 + (size_t)(tm * 8 + r);
        ushort4 o;
        o.x = f2bf(acc[r][0] + bi[0]);
        o.y = f2bf(acc[r][1] + bi[1]);
        o.z = f2bf(acc[r][2] + bi[2]);
        o.w = f2bf(acc[r][3] + bi[3]);
        *(ushort4*)&xpb[row * DC_ + tn * 4] = o;
    }
}

// ---------------------------------------------------------------- fused distance MFMA + lse + argmax + loss
// Block: 64 rows x all 1024 codes. 4 waves, 16 rows/wave (B-operand),
// codes are the MFMA M-dim (A-operand) -> per-lane-local row reduction.
__global__ __launch_bounds__(256) void dist_k(
    const unsigned short* __restrict__ xpb,   // (M,128) bf16
    const unsigned short* __restrict__ embb,  // (K,128) bf16
    const float* __restrict__ e2h,            // (K) |e|^2/128
    const int*   __restrict__ tlc,            // (B, NQ, T)
    int iq,
    int* __restrict__ ind, float* __restrict__ accp)
{
    __shared__ short lxp[64 * 128];
    __shared__ short lem[2][64 * 128];
    __shared__ float le2[K_];
    __shared__ float sred[64];

    const int tid  = threadIdx.x;
    const int lane = tid & 63;
    const int wv   = tid >> 6;
    const int row0 = blockIdx.x * 64;
    const int l15  = lane & 15;
    const int lg4  = lane >> 4;

    // stage xp tile (XOR-swizzled: short_idx ^ ((row&7)<<3))
    {
        const unsigned short* xr = xpb + (size_t)row0 * DC_;
        #pragma unroll
        for (int i2 = 0; i2 < 4; ++i2) {
            int gi = tid + 256 * i2;
            int r = gi >> 4, sl = gi & 15;
            int4 v = *(const int4*)(xr + r * 128 + sl * 8);
            *(int4*)&lxp[(r * 128 + sl * 8) ^ ((r & 7) << 3)] = v;
        }
        *(float4*)&le2[tid * 4] = *(const float4*)&e2h[tid * 4];
        #pragma unroll
        for (int i2 = 0; i2 < 4; ++i2) {
            int gi = tid + 256 * i2;
            int r = gi >> 4, sl = gi & 15;
            int4 v = *(const int4*)(embb + r * 128 + sl * 8);
            *(int4*)&lem[0][(r * 128 + sl * 8) ^ ((r & 7) << 3)] = v;
        }
    }

    // per-lane target bookkeeping (row = row0 + wv*16 + l15)
    const int grow = row0 + wv * 16 + l15;
    const int bb = grow >> 12, tt = grow & (T_ - 1);
    const int tgt = tlc[(size_t)bb * (NQn * T_) + (size_t)iq * T_ + tt];
    const int myf = (((tgt >> 2) & 3) == lg4) ? (tgt >> 4) : -1;
    const int tj  = tgt & 3;

    __syncthreads();

    // xp fragments: constant for the whole kernel (16 rows of this wave)
    bf16x8 bx[4];
    {
        int br = wv * 16 + l15;
        #pragma unroll
        for (int s = 0; s < 4; ++s)
            bx[s] = *(bf16x8*)&lxp[(br * 128 + s * 32 + lg4 * 8) ^ ((br & 7) << 3)];
    }

    float bv = -INFINITY, lsum = 0.f, pick = 0.f;
    int bi = 0;

    #pragma unroll 1
    for (int c = 0; c < 16; ++c) {
        const int cur = c & 1;
        int4 st0, st1, st2, st3;
        if (c < 15) {
            const unsigned short* eb = embb + (size_t)(c + 1) * 64 * 128;
            int gi, r, sl;
            gi = tid;       r = gi >> 4; sl = gi & 15; st0 = *(const int4*)(eb + r * 128 + sl * 8);
            gi = tid + 256; r = gi >> 4; sl = gi & 15; st1 = *(const int4*)(eb + r * 128 + sl * 8);
            gi = tid + 512; r = gi >> 4; sl = gi & 15; st2 = *(const int4*)(eb + r * 128 + sl * 8);
            gi = tid + 768; r = gi >> 4; sl = gi & 15; st3 = *(const int4*)(eb + r * 128 + sl * 8);
        }
        #pragma unroll
        for (int f = 0; f < 4; ++f) {
            const int ar = f * 16 + l15;
            f32x4 acc = {0.f, 0.f, 0.f, 0.f};
            #pragma unroll
            for (int s = 0; s < 4; ++s) {
                bf16x8 ax = *(bf16x8*)&lem[cur][(ar * 128 + s * 32 + lg4 * 8) ^ ((ar & 7) << 3)];
                acc = __builtin_amdgcn_mfma_f32_16x16x32_bf16(ax, bx[s], acc, 0, 0, 0);
            }
            float4 e2v = *(const float4*)&le2[c * 64 + f * 16 + lg4 * 4];
            // logits = dot/64 - e2/128
            float lg0 = fmaf(acc[0], 0.015625f, -e2v.x);
            float lg1 = fmaf(acc[1], 0.015625f, -e2v.y);
            float lg2 = fmaf(acc[2], 0.015625f, -e2v.z);
            float lg3 = fmaf(acc[3], 0.015625f, -e2v.w);
            // local argmax (strict >, ascending index => first-occurrence ties)
            float v01 = fmaxf(lg0, lg1); int j01 = (lg1 > lg0) ? 1 : 0;
            float v23 = fmaxf(lg2, lg3); int j23 = (lg3 > lg2) ? 3 : 2;
            float lm  = fmaxf(v01, v23); int jl  = (v23 > v01) ? j23 : j01;
            const int cb = c * 64 + f * 16 + lg4 * 4;
            if (lm > bv) bi = cb + jl;
            float nm = fmaxf(bv, lm);
            lsum = lsum * __expf(bv - nm) + __expf(lg0 - nm) + __expf(lg1 - nm)
                 + __expf(lg2 - nm) + __expf(lg3 - nm);
            bv = nm;
            const int gf = c * 4 + f;
            if (gf == myf)
                pick = (tj == 0) ? lg0 : ((tj == 1) ? lg1 : ((tj == 2) ? lg2 : lg3));
        }
        if (c < 15) {
            short* dst = lem[cur ^ 1];
            int gi, r, sl;
            gi = tid;       r = gi >> 4; sl = gi & 15; *(int4*)&dst[(r * 128 + sl * 8) ^ ((r & 7) << 3)] = st0;
            gi = tid + 256; r = gi >> 4; sl = gi & 15; *(int4*)&dst[(r * 128 + sl * 8) ^ ((r & 7) << 3)] = st1;
            gi = tid + 512; r = gi >> 4; sl = gi & 15; *(int4*)&dst[(r * 128 + sl * 8) ^ ((r & 7) << 3)] = st2;
            gi = tid + 768; r = gi >> 4; sl = gi & 15; *(int4*)&dst[(r * 128 + sl * 8) ^ ((r & 7) << 3)] = st3;
            __syncthreads();
        }
    }

    // combine the 4 lane-groups (each holds 256 codes for this row)
    #pragma unroll
    for (int off = 16; off <= 32; off <<= 1) {
        float om = __shfl_xor(bv, off);
        float ol = __shfl_xor(lsum, off);
        int   ob = __shfl_xor(bi, off);
        float op = __shfl_xor(pick, off);
        bool take = (om > bv) || (om == bv && ob < bi);
        float nm = fmaxf(bv, om);
        lsum = lsum * __expf(bv - nm) + ol * __expf(om - nm);
        if (take) bi = ob;
        bv = nm;
        pick += op;
    }

    if (lane < 16) {
        ind[grow] = bi;
        sred[wv * 16 + lane] = (bv + __logf(lsum)) - pick;
    }
    __syncthreads();
    if (tid < 64) {
        float v = sred[tid];
        #pragma unroll
        for (int off = 1; off < 64; off <<= 1) v += __shfl_xor(v, off);
        if (tid == 0) atomicAdd(accp, v);
    }
}

// ---------------------------------------------------------------- table[k][d] = embed[k]·Wout[d] + b_out[d]
__global__ __launch_bounds__(256) void table_k(
    const float* __restrict__ emb, const float* __restrict__ Wout,
    const float* __restrict__ bout, float* __restrict__ table)
{
    __shared__ float se[4][DC_];
    int k0 = blockIdx.x * 4;
    int tid = threadIdx.x;
    #pragma unroll
    for (int it = 0; it < 2; ++it) {
        int idx = it * 256 + tid;
        se[idx >> 7][idx & 127] = emb[(size_t)k0 * DC_ + idx];
    }
    __syncthreads();
    int d = tid;
    const float4* wrow = (const float4*)(Wout + (size_t)d * DC_);
    float a0 = 0.f, a1 = 0.f, a2 = 0.f, a3 = 0.f;
    #pragma unroll
    for (int c4 = 0; c4 < 32; ++c4) {
        float4 w  = wrow[c4];
        float4 q0 = *(const float4*)&se[0][c4 * 4];
        float4 q1 = *(const float4*)&se[1][c4 * 4];
        float4 q2 = *(const float4*)&se[2][c4 * 4];
        float4 q3 = *(const float4*)&se[3][c4 * 4];
        a0 += w.x * q0.x + w.y * q0.y + w.z * q0.z + w.w * q0.w;
        a1 += w.x * q1.x + w.y * q1.y + w.z * q1.z + w.w * q1.w;
        a2 += w.x * q2.x + w.y * q2.y + w.z * q2.z + w.w * q2.w;
        a3 += w.x * q3.x + w.y * q3.y + w.z * q3.z + w.w * q3.w;
    }
    float bo = bout[d];
    table[(size_t)(k0 + 0) * D_ + d] = a0 + bo;
    table[(size_t)(k0 + 1) * D_ + d] = a1 + bo;
    table[(size_t)(k0 + 2) * D_ + d] = a2 + bo;
    table[(size_t)(k0 + 3) * D_ + d] = a3 + bo;
}

// ---------------------------------------------------------------- residual -= table[ind]
__global__ __launch_bounds__(256) void update_k(
    const float* __restrict__ src, const float* __restrict__ table,
    const int* __restrict__ ind, float* __restrict__ dst)
{
    __shared__ int sk[64];
    const int b  = blockIdx.x >> 6;
    const int t0 = (blockIdx.x & 63) << 6;
    const int tid = threadIdx.x;
    if (tid < 64) sk[tid] = ind[(size_t)b * T_ + t0 + tid];
    __syncthreads();
    const int t4 = (tid & 15) * 4;
    const int dg = tid >> 4;
    const int k0 = sk[t4], k1 = sk[t4 + 1], k2 = sk[t4 + 2], k3 = sk[t4 + 3];
    #pragma unroll
    for (int dl = 0; dl < 16; ++dl) {
        int d = dl * 16 + dg;
        size_t base = ((size_t)b * D_ + d) * T_ + t0 + t4;
        float4 v = *(const float4*)&src[base];
        float4 o;
        o.x = v.x - table[(size_t)k0 * D_ + d];
        o.y = v.y - table[(size_t)k1 * D_ + d];
        o.z = v.z - table[(size_t)k2 * D_ + d];
        o.w = v.w - table[(size_t)k3 * D_ + d];
        *(float4*)&dst[base] = o;
    }
}

// ---------------------------------------------------------------- launch
extern "C" void kernel_launch(void* const* d_in, const int* in_sizes, int n_in,
                              void* d_out, int out_size, void* d_ws, size_t ws_size,
                              hipStream_t stream)
{
    (void)in_sizes; (void)n_in; (void)out_size; (void)ws_size;
    const float* dstart = (const float*)d_in[0];
    const int*   tlc    = (const int*)d_in[1];
    const float* Win    = (const float*)d_in[2];
    const float* bin    = (const float*)d_in[3];
    const float* Wout   = (const float*)d_in[4];
    const float* bout   = (const float*)d_in[5];
    const float* emb    = (const float*)d_in[6];

    char* ws = (char*)d_ws;
    size_t off = 0;
    float*          xres  = (float*)(ws + off);          off += (size_t)B_ * D_ * T_ * 4;  // 67.1 MB
    unsigned short* xpb   = (unsigned short*)(ws + off); off += (size_t)M_ * DC_ * 2;      // 16.8 MB
    unsigned short* embb  = (unsigned short*)(ws + off); off += (size_t)4 * K_ * DC_ * 2;  // 1 MB
    float*          e2h   = (float*)(ws + off);          off += (size_t)4 * K_ * 4;
    int*            ind   = (int*)(ws + off);            off += (size_t)M_ * 4;
    float*          table = (float*)(ws + off);          off += (size_t)K_ * D_ * 4;
    float*          accp  = (float*)(ws + off);          off += 256;

    zero_acc_k<<<1, 1, 0, stream>>>(accp);
    conv_emb_k<<<256, 256, 0, stream>>>(emb, embb, e2h);

    for (int i = 0; i < 4; ++i) {
        const float* srcX = (i == 0) ? dstart : xres;
        xp_gemm_k<<<1024, 256, 0, stream>>>(srcX, Win + (size_t)i * DC_ * D_,
                                            bin + (size_t)i * DC_, xpb);
        dist_k<<<1024, 256, 0, stream>>>(xpb, embb + (size_t)i * K_ * DC_,
                                         e2h + (size_t)i * K_, tlc, i, ind, accp);
        if (i < 3) {
            table_k<<<256, 256, 0, stream>>>(emb + (size_t)i * K_ * DC_,
                                             Wout + (size_t)i * D_ * DC_,
                                             bout + (size_t)i * D_, table);
            update_k<<<1024, 256, 0, stream>>>((i == 0) ? dstart : xres,
                                               table, ind, xres);
        }
    }
    final_k<<<1, 1, 0, stream>>>(accp, (float*)d_out);
}

// Round 3
// 271.855 us; speedup vs baseline: 6.6786x; 2.1152x over previous
//
#include <hip/hip_runtime.h>
#include <math.h>

#define B_   16
#define D_   256
#define T_   4096
#define NQn  8
#define K_   1024
#define DC_  128
#define M_   65536

typedef short bf16x8 __attribute__((ext_vector_type(8)));
typedef float f32x4  __attribute__((ext_vector_type(4)));

static __device__ __forceinline__ unsigned short f2bf(float f) {
    unsigned u = __float_as_uint(f);
    unsigned r = (u + 0x7fffu + ((u >> 16) & 1u)) >> 16;
    return (unsigned short)r;
}
static __device__ __forceinline__ float bf2f(unsigned short h) {
    return __uint_as_float(((unsigned)h) << 16);
}

__global__ void zero_acc_k(float* acc) { acc[0] = 0.f; }
__global__ void final_k(const float* __restrict__ acc, float* __restrict__ out) {
    out[0] = acc[0] * (1.f / 262144.f);   // / (4 * B * T)
}

// ---------------------------------------------------------------- transpose+convert
// X (B, D, T) f32  ->  Xb (M = B*T rows, 256 d) bf16 row-major
__global__ __launch_bounds__(256) void tr_k(
    const float* __restrict__ X, unsigned short* __restrict__ Xb)
{
    __shared__ float tile[64][65];
    const int bid = blockIdx.x;
    const int b = bid >> 8, tt = (bid >> 2) & 63, dt = bid & 3;
    const int tid = threadIdx.x;
    #pragma unroll
    for (int it = 0; it < 4; ++it) {
        int lin = it * 1024 + tid * 4;
        int dd = lin >> 6, tv = lin & 63;
        const float* src = X + ((size_t)(b * 256 + dt * 64 + dd)) * 4096 + tt * 64 + tv;
        float4 v = *(const float4*)src;
        tile[dd][tv] = v.x; tile[dd][tv + 1] = v.y;
        tile[dd][tv + 2] = v.z; tile[dd][tv + 3] = v.w;
    }
    __syncthreads();
    #pragma unroll
    for (int it = 0; it < 4; ++it) {
        int lin = it * 1024 + tid * 4;
        int tr = lin >> 6, d0 = lin & 63;
        ushort4 o;
        o.x = f2bf(tile[d0][tr]);     o.y = f2bf(tile[d0 + 1][tr]);
        o.z = f2bf(tile[d0 + 2][tr]); o.w = f2bf(tile[d0 + 3][tr]);
        *(ushort4*)&Xb[((size_t)(b * 4096 + tt * 64 + tr)) * 256 + dt * 64 + d0] = o;
    }
}

// ---------------------------------------------------------------- precompute
// F'[k][d] = (embed[k]·Win[:,d]) / 64    (bf16, unit-swizzled for conflict-free ds_read)
// g[k]     = (|e_k|^2 - 2 b_in·e_k)/128
// table[k][d] = embed[k]·Wout[d] + b_out[d]   (bf16, natural layout)
__global__ __launch_bounds__(256) void prep_k(
    const float* __restrict__ Win,   // (8,128,256)
    const float* __restrict__ bin,   // (8,128)
    const float* __restrict__ Wout,  // (8,256,128)
    const float* __restrict__ bout,  // (8,256)
    const float* __restrict__ emb,   // (8,1024,128)
    unsigned short* __restrict__ Fz, // (4,1024,256) swizzled bf16
    unsigned short* __restrict__ tab,// (3,1024,256) bf16
    float* __restrict__ g)           // (4,1024)
{
    __shared__ float E[16][128];
    __shared__ float sb[128];
    const int iq = blockIdx.x >> 6;
    const int k0 = (blockIdx.x & 63) << 4;
    const int tid = threadIdx.x;
    {
        const float* src = emb + ((size_t)iq * K_ + k0) * DC_;
        #pragma unroll
        for (int it = 0; it < 2; ++it) {
            int lin = it * 1024 + tid * 4;
            float4 v = *(const float4*)(src + lin);
            *(float4*)&E[lin >> 7][lin & 127] = v;
        }
        if (tid < 32) *(float4*)&sb[tid * 4] = *(const float4*)(bin + iq * DC_ + tid * 4);
    }
    __syncthreads();
    if (tid < 16) {
        float e2 = 0.f, be = 0.f;
        for (int c2 = 0; c2 < 128; ++c2) {
            float e = E[tid][c2];
            e2 += e * e; be += sb[c2] * e;
        }
        g[iq * K_ + k0 + tid] = (e2 - 2.f * be) * (1.f / 128.f);
    }
    {
        const int d = tid;
        float acc[16];
        #pragma unroll
        for (int kk = 0; kk < 16; ++kk) acc[kk] = 0.f;
        const float* wp = Win + (size_t)iq * DC_ * D_ + d;
        for (int c2 = 0; c2 < 128; ++c2) {
            float w = wp[(size_t)c2 * D_];
            #pragma unroll
            for (int kk = 0; kk < 16; ++kk) acc[kk] = fmaf(E[kk][c2], w, acc[kk]);
        }
        unsigned short* Fq = Fz + ((size_t)iq << 18);
        const int j = d >> 3, dl = d & 7;
        #pragma unroll
        for (int kk = 0; kk < 16; ++kk) {
            int kg = k0 + kk;
            int unit = (kg << 5) + (j ^ (kg & 7));
            Fq[(unit << 3) + dl] = f2bf(acc[kk] * 0.015625f);
        }
    }
    if (iq < 3) {
        const int d = tid;
        float acc[16];
        #pragma unroll
        for (int kk = 0; kk < 16; ++kk) acc[kk] = 0.f;
        const float* wp = Wout + ((size_t)iq * D_ + d) * DC_;
        for (int c2 = 0; c2 < 128; ++c2) {
            float w = wp[c2];
            #pragma unroll
            for (int kk = 0; kk < 16; ++kk) acc[kk] = fmaf(E[kk][c2], w, acc[kk]);
        }
        float bo = bout[iq * D_ + d];
        unsigned short* tq = tab + ((size_t)iq << 18);
        #pragma unroll
        for (int kk = 0; kk < 16; ++kk)
            tq[((size_t)(k0 + kk) << 8) + d] = f2bf(acc[kk] + bo);
    }
}

// ---------------------------------------------------------------- fused 4-quantizer RVQ
// 256 blocks x 512 threads (8 waves). Wave owns 32 rows; lane holds 2 rows x 64 k
// of the residual in bf16 registers. Per quantizer: 16 double-buffered F chunks
// (global_load_lds), MFMA vs all 1024 codes, in-register lse/argmax/pick,
// in-register residual update via table gather.
__global__ __launch_bounds__(512) void rvq_k(
    const unsigned short* __restrict__ Xb,
    const unsigned short* __restrict__ Fz,
    const unsigned short* __restrict__ tab,
    const float* __restrict__ g,
    const int* __restrict__ tlc,
    float* __restrict__ accp)
{
    __shared__ __align__(16) char lF[2][32768];
    __shared__ float lgq[4096];

    const int tid  = threadIdx.x;
    const int lane = tid & 63;
    const int wv   = tid >> 6;
    const int l15  = lane & 15;
    const int lg4  = lane >> 4;
    const int row_base = blockIdx.x * 256 + wv * 32;

    #pragma unroll
    for (int i = 0; i < 8; ++i) lgq[tid + 512 * i] = g[tid + 512 * i];

    bf16x8 xb[2][8];
    #pragma unroll
    for (int rf = 0; rf < 2; ++rf) {
        const unsigned short* xr = Xb + (size_t)(row_base + rf * 16 + l15) * 256 + lg4 * 8;
        #pragma unroll
        for (int s = 0; s < 8; ++s) xb[rf][s] = *(const bf16x8*)(xr + s * 32);
    }

    {   // prologue: stage chunk 0 of quantizer 0
        const char* src = (const char*)Fz;
        #pragma unroll
        for (int is = 0; is < 4; ++is)
            __builtin_amdgcn_global_load_lds(
                (const __attribute__((address_space(1))) unsigned int*)(src + is * 8192 + wv * 1024 + (lane << 4)),
                (__attribute__((address_space(3))) unsigned int*)&lF[0][is * 8192 + wv * 1024],
                16, 0, 0);
    }
    __syncthreads();

    float loss = 0.f;

    #pragma unroll 1
    for (int q = 0; q < 4; ++q) {
        const float* gq = lgq + (q << 10);
        int tgt[2];
        #pragma unroll
        for (int rf = 0; rf < 2; ++rf) {
            int row = row_base + rf * 16 + l15;
            tgt[rf] = tlc[(size_t)(row >> 12) * (NQn * T_) + q * T_ + (row & (T_ - 1))];
        }
        float lsum[2] = {0.f, 0.f};
        float bv[2] = {-1e30f, -1e30f};
        int   bi[2] = {0, 0};
        float pick[2] = {0.f, 0.f};

        #pragma unroll 1
        for (int c = 0; c < 16; ++c) {
            const int cur = c & 1;
            if (!(c == 15 && q == 3)) {
                const char* src = (c < 15)
                    ? (const char*)Fz + ((size_t)q << 19) + ((size_t)(c + 1) << 15)
                    : (const char*)Fz + ((size_t)(q + 1) << 19);
                #pragma unroll
                for (int is = 0; is < 4; ++is)
                    __builtin_amdgcn_global_load_lds(
                        (const __attribute__((address_space(1))) unsigned int*)(src + is * 8192 + wv * 1024 + (lane << 4)),
                        (__attribute__((address_space(3))) unsigned int*)&lF[cur ^ 1][is * 8192 + wv * 1024],
                        16, 0, 0);
            }
            #pragma unroll
            for (int cf = 0; cf < 4; ++cf) {
                bf16x8 af[8];
                const int cl = cf * 16 + l15;
                const int swb = cl << 5;
                const int sx = cl & 7;
                #pragma unroll
                for (int s = 0; s < 8; ++s) {
                    int unit = swb + (((s << 2) + lg4) ^ sx);
                    af[s] = *(const bf16x8*)&lF[cur][unit << 4];
                }
                #pragma unroll
                for (int rf = 0; rf < 2; ++rf) {
                    f32x4 acc = {0.f, 0.f, 0.f, 0.f};
                    #pragma unroll
                    for (int s = 0; s < 8; ++s)
                        acc = __builtin_amdgcn_mfma_f32_16x16x32_bf16(af[s], xb[rf][s], acc, 0, 0, 0);
                    const int cb = (c << 6) + (cf << 4) + (lg4 << 2);
                    float4 gv = *(const float4*)&gq[cb];
                    float l0 = acc[0] - gv.x, l1 = acc[1] - gv.y;
                    float l2 = acc[2] - gv.z, l3 = acc[3] - gv.w;
                    lsum[rf] += (__expf(l0) + __expf(l1)) + (__expf(l2) + __expf(l3));
                    float m01 = fmaxf(l0, l1), m23 = fmaxf(l2, l3);
                    float lm = fmaxf(m01, m23);
                    int jl = (m23 > m01) ? ((l3 > l2) ? 3 : 2) : ((l1 > l0) ? 1 : 0);
                    if (lm > bv[rf]) { bv[rf] = lm; bi[rf] = cb + jl; }
                    int myj = tgt[rf] & 3;
                    float pj = (myj == 0) ? l0 : ((myj == 1) ? l1 : ((myj == 2) ? l2 : l3));
                    if ((tgt[rf] >> 2) == (cb >> 2)) pick[rf] = pj;
                }
            }
            __syncthreads();
        }
        #pragma unroll
        for (int rf = 0; rf < 2; ++rf) {
            #pragma unroll
            for (int off = 16; off <= 32; off <<= 1) {
                lsum[rf] += __shfl_xor(lsum[rf], off);
                pick[rf] += __shfl_xor(pick[rf], off);
                float om = __shfl_xor(bv[rf], off);
                int   ob = __shfl_xor(bi[rf], off);
                if (om > bv[rf] || (om == bv[rf] && ob < bi[rf])) { bv[rf] = om; bi[rf] = ob; }
            }
        }
        if (lane < 16)
            loss += (__logf(lsum[0]) - pick[0]) + (__logf(lsum[1]) - pick[1]);
        if (q < 3) {
            const unsigned short* tq = tab + ((size_t)q << 18);
            #pragma unroll
            for (int rf = 0; rf < 2; ++rf) {
                const unsigned short* trow = tq + ((size_t)bi[rf] << 8) + lg4 * 8;
                #pragma unroll
                for (int s = 0; s < 8; ++s) {
                    bf16x8 tv = *(const bf16x8*)(trow + s * 32);
                    bf16x8 xv = xb[rf][s];
                    #pragma unroll
                    for (int j = 0; j < 8; ++j)
                        xv[j] = (short)f2bf(bf2f((unsigned short)xv[j]) - bf2f((unsigned short)tv[j]));
                    xb[rf][s] = xv;
                }
            }
        }
    }
    #pragma unroll
    for (int off = 1; off < 64; off <<= 1) loss += __shfl_xor(loss, off);
    if (lane == 0) atomicAdd(accp, loss);
}

// ---------------------------------------------------------------- launch
extern "C" void kernel_launch(void* const* d_in, const int* in_sizes, int n_in,
                              void* d_out, int out_size, void* d_ws, size_t ws_size,
                              hipStream_t stream)
{
    (void)in_sizes; (void)n_in; (void)out_size; (void)ws_size;
    const float* dstart = (const float*)d_in[0];
    const int*   tlc    = (const int*)d_in[1];
    const float* Win    = (const float*)d_in[2];
    const float* bin    = (const float*)d_in[3];
    const float* Wout   = (const float*)d_in[4];
    const float* bout   = (const float*)d_in[5];
    const float* emb    = (const float*)d_in[6];

    char* ws = (char*)d_ws;
    size_t off = 0;
    unsigned short* Xb  = (unsigned short*)(ws + off); off += (size_t)M_ * D_ * 2;        // 33.6 MB
    unsigned short* Fz  = (unsigned short*)(ws + off); off += (size_t)4 * K_ * D_ * 2;    // 2 MB
    unsigned short* tab = (unsigned short*)(ws + off); off += (size_t)3 * K_ * D_ * 2;    // 1.5 MB
    float*          g   = (float*)(ws + off);          off += (size_t)4 * K_ * 4;
    float*          accp= (float*)(ws + off);          off += 256;

    zero_acc_k<<<1, 1, 0, stream>>>(accp);
    tr_k<<<4096, 256, 0, stream>>>(dstart, Xb);
    prep_k<<<256, 256, 0, stream>>>(Win, bin, Wout, bout, emb, Fz, tab, g);
    rvq_k<<<256, 512, 0, stream>>>(Xb, Fz, tab, g, tlc, accp);
    final_k<<<1, 1, 0, stream>>>(accp, (float*)d_out);
}